// Round 1
// baseline (1918.762 us; speedup 1.0000x reference)
//
#include <hip/hip_runtime.h>
#include <hip/hip_bf16.h>

// MSCN fused pipeline, MI355X gfx950. Round 0: f32 correctness baseline.
// B=64, C=512, H=W=7 (N=49), HY=WY=28 (N1=784), heads=8, d=64, SCALE=0.125
// kc1 = 784//2 = 392, kc2 = 784//3 = 261

typedef __hip_bfloat16 bf16;

#define DI __device__ __forceinline__

DI float bfu(unsigned short u) { return __uint_as_float(((unsigned int)u) << 16); }
DI float blo(unsigned int u) { return __uint_as_float(u << 16); }
DI float bhi(unsigned int u) { return __uint_as_float(u & 0xFFFF0000u); }

DI float wave_max_f(float v) {
#pragma unroll
  for (int off = 32; off; off >>= 1) v = fmaxf(v, __shfl_xor(v, off, 64));
  return v;
}
DI float wave_sum_f(float v) {
#pragma unroll
  for (int off = 32; off; off >>= 1) v += __shfl_xor(v, off, 64);
  return v;
}
DI int wave_sum_i(int v) {
#pragma unroll
  for (int off = 32; off; off >>= 1) v += __shfl_xor(v, off, 64);
  return v;
}
// monotone float->uint key: ascending key order == ascending float order
DI unsigned int fkey(float f) {
  unsigned int u = __float_as_uint(f);
  return (u & 0x80000000u) ? ~u : (u | 0x80000000u);
}

// ---------------------------------------------------------------- pool
// pooled(b,c,i,j) = sum_k 1/k^2 * box_k, zero-padded, count_include_pad
__global__ __launch_bounds__(256) void pool_kernel(const float* __restrict__ y,
                                                   bf16* __restrict__ pooled) {
  const int plane = blockIdx.x;  // b*512 + c
  const float* src = y + (size_t)plane * 784;
  __shared__ float p[784];
  for (int i = threadIdx.x; i < 784; i += 256) p[i] = src[i];
  __syncthreads();
  for (int i = threadIdx.x; i < 784; i += 256) {
    int r = i / 28, c = i - (i / 28) * 28;
    float acc = 0.f;
#pragma unroll
    for (int di = -3; di <= 3; ++di) {
      int rr = r + di;
      if (rr < 0 || rr >= 28) continue;
#pragma unroll
      for (int dj = -3; dj <= 3; ++dj) {
        int cc = c + dj;
        if (cc < 0 || cc >= 28) continue;
        const int adi = di < 0 ? -di : di, adj = dj < 0 ? -dj : dj;
        const float w = 1.0f / 49.0f + ((adi <= 2 && adj <= 2) ? 1.0f / 25.0f : 0.0f) +
                        ((adi <= 1 && adj <= 1) ? 1.0f / 9.0f : 0.0f);
        acc += w * p[rr * 28 + cc];
      }
    }
    pooled[(size_t)plane * 784 + i] = __float2bfloat16(acc);
  }
}

// ---------------------------------------------------------------- layernorm + transpose
// pooled [B,C,784] -> yln [B,784,C], LN over C
__global__ __launch_bounds__(256) void ln_kernel(const bf16* __restrict__ pooled,
                                                 const float* __restrict__ gamma,
                                                 const float* __restrict__ beta,
                                                 bf16* __restrict__ yln) {
  const int b = blockIdx.y;
  const int n0 = blockIdx.x * 16;
  __shared__ float tile[16][520];  // [pixel][c], pad to dodge worst conflicts
  __shared__ float smu[16], srs[16];
  const bf16* src = pooled + (size_t)b * 512 * 784;
  for (int idx = threadIdx.x; idx < 512 * 16; idx += 256) {
    int c = idx >> 4, pp = idx & 15;
    tile[pp][c] = __bfloat162float(src[(size_t)c * 784 + n0 + pp]);
  }
  __syncthreads();
  int pp = threadIdx.x >> 4, l = threadIdx.x & 15;
  float s = 0.f, s2 = 0.f;
  for (int c = l; c < 512; c += 16) {
    float v = tile[pp][c];
    s += v;
    s2 += v * v;
  }
#pragma unroll
  for (int off = 8; off; off >>= 1) {
    s += __shfl_xor(s, off, 64);
    s2 += __shfl_xor(s2, off, 64);
  }
  if (l == 0) {
    float mu = s * (1.f / 512.f);
    float var = s2 * (1.f / 512.f) - mu * mu;
    smu[pp] = mu;
    srs[pp] = rsqrtf(var + 1e-5f);
  }
  __syncthreads();
  bf16* dst = yln + ((size_t)b * 784 + n0) * 512;
  for (int idx = threadIdx.x; idx < 512 * 16; idx += 256) {
    int q = idx >> 9, c = idx & 511;
    float v = (tile[q][c] - smu[q]) * srs[q] * gamma[c] + beta[c];
    dst[(size_t)q * 512 + c] = __float2bfloat16(v);
  }
}

// ---------------------------------------------------------------- x transpose
// x [B,C,49] -> xsT [B,49,C]
__global__ __launch_bounds__(256) void xst_kernel(const float* __restrict__ x,
                                                  float* __restrict__ xsT) {
  int idx = blockIdx.x * 256 + threadIdx.x;  // grid sized exactly
  int c = idx & 511;
  int rem = idx >> 9;
  int r = rem % 49, b = rem / 49;
  xsT[idx] = x[((size_t)b * 512 + c) * 49 + r];
}

// ---------------------------------------------------------------- GEMM (f32 acc)
DI float4 ldg4(const float* p) { return *reinterpret_cast<const float4*>(p); }
DI float4 ldg4(const bf16* p) {
  ushort4 u = *reinterpret_cast<const ushort4*>(p);
  return make_float4(bfu(u.x), bfu(u.y), bfu(u.z), bfu(u.w));
}

// MODE 0: Q  -> o0 f32 [B,8,49,64]
// MODE 1: KV -> oK/oV bf16 [B,8,784,64]
// MODE 2: proj -> o0 f32 [B,512,49] (transposed write) + bias
template <int BM, int BN, int BK, int TM, int TN, int MODE, typename AT>
__global__ __launch_bounds__(256) void gemm_k(const AT* __restrict__ A, const float* __restrict__ B,
                                              int M, int N, int K, float* __restrict__ o0,
                                              bf16* __restrict__ oK, bf16* __restrict__ oV,
                                              const float* __restrict__ bias) {
  __shared__ float As[BK][BM + 4];
  __shared__ float Bs[BK][BN + 4];
  const int tid = threadIdx.x;
  const int tx = tid & 15, ty = tid >> 4;
  const int m0 = blockIdx.y * BM, n0 = blockIdx.x * BN;
  float acc[TM][TN];
#pragma unroll
  for (int i = 0; i < TM; ++i)
#pragma unroll
    for (int j = 0; j < TN; ++j) acc[i][j] = 0.f;

  for (int k0 = 0; k0 < K; k0 += BK) {
#pragma unroll
    for (int t = 0; t < (BM * BK) / 1024; ++t) {
      int lin = tid * 4 + t * 1024;
      int mm = lin / BK, kk = lin % BK;
      float4 v = ldg4(A + (size_t)(m0 + mm) * K + k0 + kk);
      As[kk + 0][mm] = v.x;
      As[kk + 1][mm] = v.y;
      As[kk + 2][mm] = v.z;
      As[kk + 3][mm] = v.w;
    }
#pragma unroll
    for (int t = 0; t < (BN * BK) / 1024; ++t) {
      int lin = tid * 4 + t * 1024;
      int kk = lin / BN, nn = lin % BN;
      *reinterpret_cast<float4*>(&Bs[kk][nn]) = ldg4(B + (size_t)(k0 + kk) * N + n0 + nn);
    }
    __syncthreads();
#pragma unroll
    for (int kk = 0; kk < BK; ++kk) {
      float a[TM], bb[TN];
#pragma unroll
      for (int i = 0; i < TM; i += 4)
        *reinterpret_cast<float4*>(&a[i]) = *reinterpret_cast<const float4*>(&As[kk][ty * TM + i]);
#pragma unroll
      for (int j = 0; j < TN; j += 4)
        *reinterpret_cast<float4*>(&bb[j]) = *reinterpret_cast<const float4*>(&Bs[kk][tx * TN + j]);
#pragma unroll
      for (int i = 0; i < TM; ++i)
#pragma unroll
        for (int j = 0; j < TN; ++j) acc[i][j] = fmaf(a[i], bb[j], acc[i][j]);
    }
    __syncthreads();
  }
#pragma unroll
  for (int i = 0; i < TM; ++i) {
    int m = m0 + ty * TM + i;
#pragma unroll
    for (int j = 0; j < TN; ++j) {
      int n = n0 + tx * TN + j;
      float v = acc[i][j];
      if constexpr (MODE == 0) {
        int b = m / 49, r = m - (m / 49) * 49;
        o0[(((size_t)b * 8 + (n >> 6)) * 49 + r) * 64 + (n & 63)] = v;
      } else if constexpr (MODE == 1) {
        int b = m / 784, n1 = m - (m / 784) * 784;
        bf16* dst = (n & 512) ? oV : oK;
        dst[(((size_t)b * 8 + ((n >> 6) & 7)) * 784 + n1) * 64 + (n & 63)] = __float2bfloat16(v);
      } else {
        int b = m / 49, r = m - (m / 49) * 49;
        o0[((size_t)b * 512 + n) * 49 + r] = v + bias[n];
      }
    }
  }
}

// ---------------------------------------------------------------- attention
// one block = (b,h, chunk of 7 q-rows). Exact top-k via 32-bit bisection.
__global__ __launch_bounds__(256) void attn_kernel(const float* __restrict__ Q,
                                                   const bf16* __restrict__ K,
                                                   const bf16* __restrict__ V,
                                                   const float* __restrict__ aw1p,
                                                   const float* __restrict__ aw2p,
                                                   float* __restrict__ aout) {
  const int bh = blockIdx.x / 7;
  const int chunk = blockIdx.x - bh * 7;
  const int b = bh >> 3, h = bh & 7;
  const int r0 = chunk * 7;
  const int tid = threadIdx.x;
  __shared__ float sQ[7][64];
  __shared__ float sA[7][784];

  const float* Qp = Q + ((size_t)bh * 49 + r0) * 64;
  for (int i = tid; i < 448; i += 256) sQ[i >> 6][i & 63] = Qp[i];
  __syncthreads();

  // QK^T * scale -> sA
  const bf16* Kp = K + (size_t)bh * (784 * 64);
  for (int idx = tid; idx < 5488; idx += 256) {
    int r = idx / 784, m = idx - (idx / 784) * 784;
    const uint4* kp = reinterpret_cast<const uint4*>(Kp + (size_t)m * 64);
    float acc = 0.f;
#pragma unroll
    for (int jj = 0; jj < 8; ++jj) {
      uint4 u = kp[jj];
      float4 q0 = *reinterpret_cast<const float4*>(&sQ[r][jj * 8]);
      float4 q1 = *reinterpret_cast<const float4*>(&sQ[r][jj * 8 + 4]);
      acc += q0.x * blo(u.x) + q0.y * bhi(u.x) + q0.z * blo(u.y) + q0.w * bhi(u.y) +
             q1.x * blo(u.z) + q1.y * bhi(u.z) + q1.z * blo(u.w) + q1.w * bhi(u.w);
    }
    sA[r][m] = acc * 0.125f;
  }
  __syncthreads();

  const float aw1 = aw1p[0], aw2 = aw2p[0];
  const int lane = tid & 63, wid = tid >> 6;
  for (int r = wid; r < 7; r += 4) {
    float v[13];
    unsigned int key[13];
#pragma unroll
    for (int i = 0; i < 13; ++i) {
      int m = lane + i * 64;
      v[i] = (m < 784) ? sA[r][m] : -INFINITY;
      key[i] = fkey(v[i]);
    }
    float mx = v[0];
#pragma unroll
    for (int i = 1; i < 13; ++i) mx = fmaxf(mx, v[i]);
    mx = wave_max_f(mx);
    // kth-largest (k=392 and k=261) via bitwise bisection on monotone keys
    unsigned int thr1 = 0u, thr2 = 0u;
    for (int bit = 31; bit >= 0; --bit) {
      unsigned int cand = thr1 | (1u << bit);
      int c = 0;
#pragma unroll
      for (int i = 0; i < 13; ++i) c += (key[i] >= cand);
      if (wave_sum_i(c) >= 392) thr1 = cand;
    }
    for (int bit = 31; bit >= 0; --bit) {
      unsigned int cand = thr2 | (1u << bit);
      int c = 0;
#pragma unroll
      for (int i = 0; i < 13; ++i) c += (key[i] >= cand);
      if (wave_sum_i(c) >= 261) thr2 = cand;
    }
    float e[13];
    float z1 = 0.f, z2 = 0.f;
#pragma unroll
    for (int i = 0; i < 13; ++i) {
      e[i] = __expf(v[i] - mx);  // pads: exp(-inf)=0
      if (key[i] >= thr1) z1 += e[i];
      if (key[i] >= thr2) z2 += e[i];
    }
    z1 = wave_sum_f(z1);
    z2 = wave_sum_f(z2);
    const float a1 = aw1 / z1, a2 = aw2 / z2;
#pragma unroll
    for (int i = 0; i < 13; ++i) {
      int m = lane + i * 64;
      if (m < 784) {
        float wgt = e[i] * (((key[i] >= thr1) ? a1 : 0.f) + ((key[i] >= thr2) ? a2 : 0.f));
        sA[r][m] = wgt;
      }
    }
  }
  __syncthreads();

  // PV: out[r][d] = sum_m w[r][m] * V[m][d]
  const int d = tid & 63, w = tid >> 6;
  const bf16* Vp = V + (size_t)bh * (784 * 64);
  float acc0 = 0.f, acc1 = 0.f;
#pragma unroll 4
  for (int m = 0; m < 784; ++m) {
    float vv = __bfloat162float(Vp[(size_t)m * 64 + d]);
    acc0 = fmaf(sA[w][m], vv, acc0);
    if (w < 3) acc1 = fmaf(sA[w + 4][m], vv, acc1);
  }
  float* op = aout + ((size_t)(b * 49 + r0 + w)) * 512 + h * 64 + d;
  *op = acc0;
  if (w < 3) op[4 * 512] = acc1;
}

// ---------------------------------------------------------------- launch
extern "C" void kernel_launch(void* const* d_in, const int* in_sizes, int n_in, void* d_out,
                              int out_size, void* d_ws, size_t ws_size, hipStream_t stream) {
  const float* x = (const float*)d_in[0];
  const float* y = (const float*)d_in[1];
  const float* Wq = (const float*)d_in[2];
  const float* Wkv = (const float*)d_in[3];
  const float* Wproj = (const float*)d_in[4];
  const float* bproj = (const float*)d_in[5];
  const float* gamma = (const float*)d_in[6];
  const float* beta = (const float*)d_in[7];
  const float* aw1 = (const float*)d_in[8];
  const float* aw2 = (const float*)d_in[9];
  float* out = (float*)d_out;

  char* w = (char*)d_ws;
  const size_t SZ = 51380224ull;      // 64*512*784*2 bytes (bf16 plane buffer)
  const size_t SMALL = 6422528ull;    // 3136*512*4 bytes
  bf16* pooled = (bf16*)(w);          // dead after ln
  bf16* yln = (bf16*)(w + SZ);        // dead after kv gemm
  bf16* Kb = (bf16*)(w);              // reuses pooled slot (after ln)
  bf16* Vb = (bf16*)(w + 2 * SZ);
  float* xsT = (float*)(w + 3 * SZ);
  float* Qf = (float*)(w + 3 * SZ + SMALL);
  float* aout = (float*)(w + 3 * SZ + 2 * SMALL);
  // peak ws use: 3*SZ + 3*SMALL = 173.4 MB

  pool_kernel<<<dim3(32768), dim3(256), 0, stream>>>(y, pooled);
  ln_kernel<<<dim3(49, 64), dim3(256), 0, stream>>>(pooled, gamma, beta, yln);
  xst_kernel<<<dim3(6272), dim3(256), 0, stream>>>(x, xsT);
  gemm_k<64, 64, 16, 4, 4, 0, float>
      <<<dim3(8, 49), dim3(256), 0, stream>>>(xsT, Wq, 3136, 512, 512, Qf, nullptr, nullptr, nullptr);
  gemm_k<128, 128, 16, 8, 8, 1, bf16>
      <<<dim3(8, 392), dim3(256), 0, stream>>>(yln, Wkv, 50176, 1024, 512, nullptr, Kb, Vb, nullptr);
  attn_kernel<<<dim3(3584), dim3(256), 0, stream>>>(Qf, Kb, Vb, aw1, aw2, aout);
  gemm_k<64, 64, 16, 4, 4, 2, float>
      <<<dim3(8, 49), dim3(256), 0, stream>>>(aout, Wproj, 3136, 512, 512, out, nullptr, nullptr, bproj);
}